// Round 6
// baseline (174.633 us; speedup 1.0000x reference)
//
#include <hip/hip_runtime.h>
#include <stdint.h>

#define M_DIM 8192
#define K_DIM 4096
#define N_DIM 4096

#define BM 256
#define BN 256
#define BKB 128   // K-bytes (=elements) per tile, i8
#define NTILES 32 // K_DIM / BKB
#define NITER 16  // NTILES / 2

typedef __attribute__((ext_vector_type(4))) int i32x4;
typedef unsigned char u8;
typedef unsigned int u32;

// ---------------- prepass: quantize x to per-row i8, w to sign i8 ----------------

__device__ __forceinline__ signed char sgn8(float f) {
  return (f > 0.0f) ? (signed char)1 : ((f < 0.0f) ? (signed char)-1 : (signed char)0);
}

// one block per row: rowmax -> scale -> quantize 4096 floats to i8
__global__ __launch_bounds__(256) void cvt_x_i8(const float* __restrict__ x,
                                                signed char* __restrict__ xq,
                                                float* __restrict__ scales) {
  const int row = blockIdx.x;
  const float4* xr = (const float4*)(x + (size_t)row * K_DIM);
  const int tid = threadIdx.x;

  float4 v[4];
#pragma unroll
  for (int k = 0; k < 4; ++k) v[k] = xr[tid * 4 + k];

  float m = 0.0f;
#pragma unroll
  for (int k = 0; k < 4; ++k) {
    m = fmaxf(m, fmaxf(fmaxf(fabsf(v[k].x), fabsf(v[k].y)),
                       fmaxf(fabsf(v[k].z), fabsf(v[k].w))));
  }
#pragma unroll
  for (int off = 32; off; off >>= 1) m = fmaxf(m, __shfl_xor(m, off));

  __shared__ float wmax[4];
  if ((tid & 63) == 0) wmax[tid >> 6] = m;
  __syncthreads();
  m = fmaxf(fmaxf(wmax[0], wmax[1]), fmaxf(wmax[2], wmax[3]));
  m = fmaxf(m, 1e-30f);

  const float inv = 127.0f / m;
  if (tid == 0) scales[row] = m / 127.0f;

  signed char q[16] __attribute__((aligned(16)));
#pragma unroll
  for (int k = 0; k < 4; ++k) {
    const float* p = (const float*)&v[k];
#pragma unroll
    for (int j = 0; j < 4; ++j) {
      float t = fminf(fmaxf(p[j] * inv, -127.0f), 127.0f);
      q[k * 4 + j] = (signed char)__float2int_rn(t);
    }
  }
  *(int4*)(xq + (size_t)row * K_DIM + tid * 16) = *(const int4*)q;
}

__global__ __launch_bounds__(256) void cvt_w_i8(const float4* __restrict__ w,
                                                int4* __restrict__ wq) {
  const int i = blockIdx.x * blockDim.x + threadIdx.x;  // 16 floats / thread
  signed char q[16] __attribute__((aligned(16)));
#pragma unroll
  for (int k = 0; k < 4; ++k) {
    float4 v = w[i * 4 + k];
    q[k * 4 + 0] = sgn8(v.x);
    q[k * 4 + 1] = sgn8(v.y);
    q[k * 4 + 2] = sgn8(v.z);
    q[k * 4 + 3] = sgn8(v.w);
  }
  wq[i] = *(const int4*)q;
}

// ---------------- GEMM ----------------

// async global->LDS, 16 B/lane. LDS dest is the WAVE-UNIFORM base (HW adds lane*16);
// global src is per-lane (pre-swizzled so the linear LDS write lands swizzled).
__device__ __forceinline__ void load16_to_lds(const u8* g, const u8* l) {
  auto gp = reinterpret_cast<const __attribute__((address_space(1))) void*>(
      reinterpret_cast<uintptr_t>(g));
  auto lp = reinterpret_cast<__attribute__((address_space(3))) void*>(
      static_cast<uint32_t>(reinterpret_cast<uintptr_t>(l)));
  __builtin_amdgcn_global_load_lds(gp, lp, 16, 0, 0);
}

__device__ __forceinline__ i32x4 lds_read(const u8* base, int byteoff) {
  return *(const i32x4*)(base + byteoff);
}

// 256x256 i8 GEMM, tile-level sync: C = s_row * (Xq (8192x4096) * Wq^T (4096x4096)).
// Depth-1 double buffer, ONE s_barrier + ONE vmcnt(0) per 128-K tile:
//   tile t (buf[t&1]): issue all 8 stage loads of t+1 into buf[~t&1];
//   24 ds_read_b128 + 64 MFMA from buf[t&1] (compiler emits fine lgkmcnt);
//   vmcnt(0) drains the 8 issues; s_barrier.
// Hazard audit: reads(t) and stages(t+1) touch DIFFERENT buffers -> intra-tile
// wave skew is safe; stages(t+1) vs reads(t+1) separated by the tile-end
// vmcnt(0)+barrier (asm "memory" clobber + barrier prevent hoisting);
// stages(t+1) vs reads(t-1) (same buffer) separated by tile-(t-1)'s barrier.
// Swizzle (both-sides): 16B chunk cc of 128B row at slot cc^(row&7), via
// pre-swizzled global source + linear global_load_lds dest; ds_read XORs same.

#define STAGE(buf, mat, half, T)                                            \
  do {                                                                      \
    const u8* _s = ((mat) ? gBh[half] : gAh[half]) + (size_t)(T) * BKB;     \
    const u8* _r = &lds[buf][mat][half][0] + ldsw;                          \
    load16_to_lds(_s, _r);                                                  \
    load16_to_lds(_s + (size_t)64 * K_DIM, _r + 8192);                      \
  } while (0)

#define STAGE_TILE(buf, T)                                                  \
  do {                                                                      \
    STAGE(buf, 0, 0, T);                                                    \
    STAGE(buf, 0, 1, T);                                                    \
    STAGE(buf, 1, 0, T);                                                    \
    STAGE(buf, 1, 1, T);                                                    \
  } while (0)

#define READ_A(buf, mbase)                                                  \
  _Pragma("unroll") for (int mi = 0; mi < 4; ++mi)                          \
  _Pragma("unroll") for (int kk = 0; kk < 2; ++kk)                          \
      af[mi][kk] = lds_read(Ab[buf], ((mbase) + mi) * 2048 + rowb + ck[kk])

#define READ_B0(buf)                                                        \
  _Pragma("unroll") for (int ni = 0; ni < 2; ++ni)                          \
  _Pragma("unroll") for (int kk = 0; kk < 2; ++kk)                          \
      b0f[ni][kk] = lds_read(Bb[buf], bofN + ni * 2048 + rowb + ck[kk])

#define READ_B1(buf)                                                        \
  _Pragma("unroll") for (int ni = 0; ni < 2; ++ni)                          \
  _Pragma("unroll") for (int kk = 0; kk < 2; ++kk)                          \
      b1f[ni][kk] = lds_read(Bb[buf], bofN + (ni + 2) * 2048 + rowb + ck[kk])

#define MFMA_Q(m0, n0, BF)                                                  \
  _Pragma("unroll") for (int kk = 0; kk < 2; ++kk)                          \
  _Pragma("unroll") for (int mi = 0; mi < 4; ++mi)                          \
  _Pragma("unroll") for (int ni = 0; ni < 2; ++ni)                          \
      acc[(m0) + mi][(n0) + ni] = __builtin_amdgcn_mfma_i32_16x16x64_i8(    \
          af[mi][kk], BF[ni][kk], acc[(m0) + mi][(n0) + ni], 0, 0, 0)

// Full compute of one tile from buf: 24 ds_reads + 64 MFMAs, setprio'd clusters.
#define COMPUTE_TILE(buf)                                                   \
  do {                                                                      \
    READ_A(buf, 0);                                                         \
    READ_B0(buf);                                                           \
    READ_B1(buf);                                                           \
    __builtin_amdgcn_s_setprio(1);                                          \
    MFMA_Q(0, 0, b0f);                                                      \
    MFMA_Q(0, 2, b1f);                                                      \
    __builtin_amdgcn_s_setprio(0);                                          \
    READ_A(buf, 4);                                                         \
    __builtin_amdgcn_s_setprio(1);                                          \
    MFMA_Q(4, 0, b0f);                                                      \
    MFMA_Q(4, 2, b1f);                                                      \
    __builtin_amdgcn_s_setprio(0);                                          \
  } while (0)

#define TILE_GATE()                                      \
  asm volatile("s_waitcnt vmcnt(0)" ::: "memory");       \
  __builtin_amdgcn_s_barrier()

__global__ __launch_bounds__(512, 2) void bingemm_kernel(const u8* __restrict__ A,
                                                         const u8* __restrict__ B,
                                                         const float* __restrict__ S,
                                                         float* __restrict__ C) {
  __shared__ __align__(16) u8 lds[2][2][2][16384];  // 128 KiB

  const int tid = threadIdx.x;
  const int wave = tid >> 6;
  const int lane = tid & 63;

  // XCD-bijective swizzle (512 blocks % 8 XCDs == 0)
  const int orig = blockIdx.x;
  const int wgid = (orig & 7) * 64 + (orig >> 3);
  const int bm = wgid >> 4;  // 0..31
  const int bn = wgid & 15;  // 0..15

  const int wm = wave >> 2;  // wave's A half
  const int wn = wave & 3;   // wave's 64-col slice

  // ---- staging addresses (per-lane global src, pre-swizzled 16B chunk) ----
  const int l3 = lane >> 3;
  const int l7 = lane & 7;
  const int csw = (l7 ^ l3) << 4;  // swizzled chunk -> byte offset in 128B row
  const u8* gA = A + (size_t)(bm * 256 + wave * 8 + l3) * K_DIM + csw;
  const u8* gB = B + (size_t)(bn * 256 + wave * 8 + l3) * K_DIM + csw;
  const u8* gAh[2] = {gA, gA + (size_t)128 * K_DIM};
  const u8* gBh[2] = {gB, gB + (size_t)128 * K_DIM};
  const int ldsw = wave * 1024;  // wave-uniform byte offset within a region issue

  // ---- ds_read fragment addressing (swizzled) ----
  const int lane15 = lane & 15;
  const int lgrp = lane >> 4;
  const int rowb = lane15 * 128;  // byte row offset; row&7 == lane&7 for frag rows
  const int ck[2] = {((lgrp ^ l7) << 4), (((4 + lgrp) ^ l7) << 4)};
  const u8* Ab[2] = {&lds[0][0][wm][0], &lds[1][0][wm][0]};
  const u8* Bb[2] = {&lds[0][1][wn >> 1][0], &lds[1][1][wn >> 1][0]};
  const int bofN = (wn & 1) * 8192;  // byte offset of wave's 64-row slice in B region

  i32x4 acc[8][4];
  {
    const i32x4 z = {0, 0, 0, 0};
#pragma unroll
    for (int i = 0; i < 8; ++i)
#pragma unroll
      for (int j = 0; j < 4; ++j) acc[i][j] = z;
  }
  i32x4 af[4][2], b0f[2][2], b1f[2][2];

  // ---- prologue: stage tile 0 into buf0, drain, sync ----
  STAGE_TILE(0, 0);
  TILE_GATE();

  for (int i = 0; i < NITER; ++i) {
    const int T1 = 2 * i + 1, T2 = 2 * i + 2;

    // ---- tile T0 = 2i (buf0); prefetch T1 -> buf1 ----
    STAGE_TILE(1, T1);
    COMPUTE_TILE(0);
    TILE_GATE();

    // ---- tile T1 (buf1); prefetch T2 -> buf0 ----
    if (i < NITER - 1) STAGE_TILE(0, T2);
    COMPUTE_TILE(1);
    TILE_GATE();
  }

  // ---- epilogue: C/D layout col=lane&15, row=(lane>>4)*4+reg; dequant ----
  const int ccol = bn * 256 + wn * 64 + lane15;
  const int crow0 = bm * 256 + wm * 128 + (lgrp << 2);
#pragma unroll
  for (int mi = 0; mi < 8; ++mi) {
#pragma unroll
    for (int j = 0; j < 4; ++j) {
      const int row = crow0 + mi * 16 + j;
      const float s = S[row];
      float* cp = C + (size_t)row * N_DIM + ccol;
#pragma unroll
      for (int ni = 0; ni < 4; ++ni) cp[ni * 16] = s * (float)acc[mi][ni][j];
    }
  }
}

// Correctness fallback if d_ws is too small for the i8 staging buffers.
__global__ __launch_bounds__(256) void fallback_kernel(const float* __restrict__ x,
                                                       const float* __restrict__ w,
                                                       float* __restrict__ out) {
  const int col = blockIdx.x * 256 + threadIdx.x;
  const int row = blockIdx.y;
  const float* xr = x + (size_t)row * K_DIM;
  const float* wr = w + (size_t)col * K_DIM;
  float acc = 0.0f;
  for (int k = 0; k < K_DIM; k += 4) {
    float4 xv = *(const float4*)&xr[k];
    float4 wv = *(const float4*)&wr[k];
    acc += (wv.x > 0.0f ? xv.x : (wv.x < 0.0f ? -xv.x : 0.0f));
    acc += (wv.y > 0.0f ? xv.y : (wv.y < 0.0f ? -xv.y : 0.0f));
    acc += (wv.z > 0.0f ? xv.z : (wv.z < 0.0f ? -xv.z : 0.0f));
    acc += (wv.w > 0.0f ? xv.w : (wv.w < 0.0f ? -xv.w : 0.0f));
  }
  out[(size_t)row * N_DIM + col] = acc;
}

extern "C" void kernel_launch(void* const* d_in, const int* in_sizes, int n_in,
                              void* d_out, int out_size, void* d_ws, size_t ws_size,
                              hipStream_t stream) {
  const float* x = (const float*)d_in[0];  // (8192, 4096) fp32
  const float* w = (const float*)d_in[1];  // (4096, 4096) fp32
  float* out = (float*)d_out;              // (8192, 4096) fp32

  const size_t x_elems = (size_t)M_DIM * K_DIM;
  const size_t w_elems = (size_t)N_DIM * K_DIM;
  const size_t need = x_elems + w_elems + (size_t)M_DIM * sizeof(float);

  if (ws_size < need) {
    dim3 fgrid(N_DIM / 256, M_DIM);
    fallback_kernel<<<fgrid, 256, 0, stream>>>(x, w, out);
    return;
  }

  signed char* xq = (signed char*)d_ws;    // 32 MiB
  signed char* wq = xq + x_elems;          // 16 MiB
  float* scales = (float*)(wq + w_elems);  // 32 KiB

  cvt_x_i8<<<M_DIM, 256, 0, stream>>>(x, xq, scales);
  cvt_w_i8<<<(int)(w_elems / 16 / 256), 256, 0, stream>>>((const float4*)w, (int4*)wq);

  bingemm_kernel<<<(M_DIM / BM) * (N_DIM / BN), 512, 0, stream>>>(
      (const u8*)xq, (const u8*)wq, scales, out);
}